// Round 1
// baseline (602.284 us; speedup 1.0000x reference)
//
#include <hip/hip_runtime.h>
#include <math.h>

// Problem dims (fixed by reference)
#define BB 32
#define DD 256
#define TT 1024
#define KK 1024
#define NN (BB*TT)          // 32768 rows

// argmin-GEMM tiling
#define BROWS 128           // rows per block
#define CCH   128           // codes per chunk
#define DSL   64            // d per slice

// ---------------------------------------------------------------------------
// ws layout (elements):
//   float wsq   [1024]      @ 0
//   float rowsq [32768]     @ 1024
//   int   idx   [32768]     @ 33792
//   int   counts[1024]      @ 66560
//   float sse   [1]         @ 67584
// total ~271 KB
// ---------------------------------------------------------------------------

// wsq[k] = sum_d W[k,d]^2 (fp64 accumulate, round once -> closest to np pairwise)
// also zeroes counts and sse each launch (ws is poisoned / left dirty between calls)
__global__ void prep_kernel(const float* __restrict__ W, float* __restrict__ wsq,
                            int* __restrict__ counts, float* __restrict__ sse) {
    const int k = blockIdx.x;          // 1024 blocks, 64 threads (one wave)
    const int lane = threadIdx.x;
    const float4 v = ((const float4*)(W + (size_t)k * DD))[lane];
    double s = (double)v.x * v.x + (double)v.y * v.y + (double)v.z * v.z + (double)v.w * v.w;
    #pragma unroll
    for (int m = 32; m > 0; m >>= 1) s += __shfl_down(s, m);
    if (lane == 0) wsq[k] = (float)s;
    if (blockIdx.x < 16) counts[blockIdx.x * 64 + lane] = 0;
    if (blockIdx.x == 0 && lane == 0) *sse = 0.0f;
}

// rowsq[n] = sum_d z[b,d,t]^2 (fp64 accumulate, round once)
// block = 256 threads covers 64 consecutive rows (t values), 4 d-groups
__global__ void rowsq_kernel(const float* __restrict__ z, float* __restrict__ rowsq) {
    __shared__ double p[4][64];
    const int lane = threadIdx.x & 63;
    const int grp  = threadIdx.x >> 6;
    const int row0 = blockIdx.x * 64;            // 512 blocks
    const int b = row0 >> 10;
    const int t = (row0 & 1023) + lane;
    const float* zp = z + (size_t)b * DD * TT + (size_t)grp * 64 * TT + t;
    double s = 0.0;
    #pragma unroll 4
    for (int d = 0; d < 64; ++d) { float v = zp[(size_t)d * TT]; s += (double)v * v; }
    p[grp][lane] = s;
    __syncthreads();
    if (threadIdx.x < 64) {
        double tot = (p[0][threadIdx.x] + p[1][threadIdx.x]) + (p[2][threadIdx.x] + p[3][threadIdx.x]);
        rowsq[row0 + threadIdx.x] = (float)tot;
    }
}

// swizzled float4 LDS index: bijective per row, spreads bank groups
__device__ __forceinline__ int swz(int r, int q) { return r * 16 + (q ^ ((r >> 3) & 7)); }

// One block: 128 rows x all 1024 codes. 16x16 threads, 8x8 register tile.
// dist mirrors np:  s1 = fl(rowsq + wsq);  v = fl(s1 - 2*dot)  (fmaf, exact 2*dot)
__global__ __launch_bounds__(256) void argmin_kernel(
    const float* __restrict__ z, const float* __restrict__ W,
    const float* __restrict__ wsq, const float* __restrict__ rowsq,
    int* __restrict__ idx_out, int* __restrict__ counts)
{
    __shared__ float4 zs[BROWS * 16];   // 32 KB
    __shared__ float4 ws[CCH * 16];     // 32 KB
    const int tid = threadIdx.x;
    const int tx = tid & 15, ty = tid >> 4;
    const int row0 = blockIdx.x * BROWS;
    const int b = row0 >> 10, t0 = row0 & 1023;
    const float* zbase = z + (size_t)b * DD * TT + t0;

    float minv[8]; int mini[8]; float rsq[8];
    #pragma unroll
    for (int i = 0; i < 8; ++i) {
        minv[i] = 3.4e38f; mini[i] = 0;
        rsq[i] = rowsq[row0 + ty * 8 + i];
    }

    for (int ch = 0; ch < KK / CCH; ++ch) {
        float acc[8][8];
        #pragma unroll
        for (int i = 0; i < 8; ++i)
            #pragma unroll
            for (int j = 0; j < 8; ++j) acc[i][j] = 0.0f;

        for (int sl = 0; sl < DD / DSL; ++sl) {
            __syncthreads();   // protect LDS from previous compute phase
            // stage z slab: 128 rows x 64 d (global: coalesced over rows)
            #pragma unroll
            for (int k = 0; k < (BROWS * DSL) / 256; ++k) {   // 32 iters
                int i = tid + k * 256;
                int r = i & 127, d = i >> 7;                  // d in 0..63
                float v = zbase[(size_t)(sl * DSL + d) * TT + r];
                ((float*)zs)[swz(r, d >> 2) * 4 + (d & 3)] = v;
            }
            // stage W chunk: 128 codes x 64 d (global: contiguous float4)
            #pragma unroll
            for (int k = 0; k < (CCH * 16) / 256; ++k) {      // 8 iters
                int i4 = tid + k * 256;
                int r = i4 >> 4, q = i4 & 15;
                float4 v = *(const float4*)(W + (size_t)(ch * CCH + r) * DD + sl * DSL + q * 4);
                ws[swz(r, q)] = v;
            }
            __syncthreads();
            // 8x8x(64d) register-tile FMA
            for (int q = 0; q < 16; ++q) {
                float4 zf[8], wf[8];
                #pragma unroll
                for (int i = 0; i < 8; ++i) zf[i] = zs[swz(ty * 8 + i, q)];
                #pragma unroll
                for (int j = 0; j < 8; ++j) wf[j] = ws[swz(tx * 8 + j, q)];
                #pragma unroll
                for (int i = 0; i < 8; ++i)
                    #pragma unroll
                    for (int j = 0; j < 8; ++j) {
                        acc[i][j] = fmaf(zf[i].x, wf[j].x, acc[i][j]);
                        acc[i][j] = fmaf(zf[i].y, wf[j].y, acc[i][j]);
                        acc[i][j] = fmaf(zf[i].z, wf[j].z, acc[i][j]);
                        acc[i][j] = fmaf(zf[i].w, wf[j].w, acc[i][j]);
                    }
            }
        }
        // score + running argmin (codes ascending -> first-min like np.argmin)
        #pragma unroll
        for (int j = 0; j < 8; ++j) {
            int c = ch * CCH + tx * 8 + j;
            float wq = wsq[c];
            #pragma unroll
            for (int i = 0; i < 8; ++i) {
                float s1 = rsq[i] + wq;                  // rounding 1 (matches np A+B)
                float v = fmaf(-2.0f, acc[i][j], s1);    // rounding 2 (matches np (A+B)-2P)
                if (v < minv[i]) { minv[i] = v; mini[i] = c; }
            }
        }
    }
    // reduce across the 16 tx lanes of each row; ties -> lowest index
    #pragma unroll
    for (int i = 0; i < 8; ++i) {
        float v = minv[i]; int ix = mini[i];
        #pragma unroll
        for (int m = 1; m < 16; m <<= 1) {
            float ov = __shfl_xor(v, m);
            int   oi = __shfl_xor(ix, m);
            if (ov < v || (ov == v && oi < ix)) { v = ov; ix = oi; }
        }
        if (tx == 0) {
            int row = row0 + ty * 8 + i;
            idx_out[row] = ix;
            atomicAdd(&counts[ix], 1);
        }
    }
}

// out[b,d,t] = fl(ze + fl(W[idx]-ze))  (straight-through, matches np roundings)
// sse += sum (W[idx]-ze)^2
__global__ void gather_loss_kernel(const float* __restrict__ z, const float* __restrict__ W,
                                   const int* __restrict__ idx, float* __restrict__ out,
                                   float* __restrict__ sse) {
    const int bd = blockIdx.x;              // 8192 blocks = B*D
    const int b = bd >> 8, d = bd & 255;
    const int t = threadIdx.x * 4;
    const int4 ix = *(const int4*)(idx + b * TT + t);
    const size_t base = (size_t)b * DD * TT + (size_t)d * TT + t;
    const float4 zv = *(const float4*)(z + base);
    float4 w;
    w.x = W[(size_t)ix.x * DD + d];
    w.y = W[(size_t)ix.y * DD + d];
    w.z = W[(size_t)ix.z * DD + d];
    w.w = W[(size_t)ix.w * DD + d];
    float ex = w.x - zv.x, ey = w.y - zv.y, ez = w.z - zv.z, ew = w.w - zv.w;
    float4 o;
    o.x = zv.x + ex; o.y = zv.y + ey; o.z = zv.z + ez; o.w = zv.w + ew;
    *(float4*)(out + base) = o;
    float local = (ex * ex + ey * ey) + (ez * ez + ew * ew);
    // block reduce
    #pragma unroll
    for (int m = 32; m > 0; m >>= 1) local += __shfl_down(local, m);
    __shared__ float wsum[4];
    if ((threadIdx.x & 63) == 0) wsum[threadIdx.x >> 6] = local;
    __syncthreads();
    if (threadIdx.x == 0) atomicAdd(sse, (wsum[0] + wsum[1]) + (wsum[2] + wsum[3]));
}

// reg_loss = 1.25 * sse / numel ; perplexity = exp(-sum p*log(p+1e-10))
__global__ void finalize_kernel(const int* __restrict__ counts, const float* __restrict__ sse,
                                float* __restrict__ out) {
    float s = 0.0f;
    for (int k = threadIdx.x; k < KK; k += 256) {
        float p = (float)counts[k] / (float)NN;
        s += p * logf(p + 1e-10f);
    }
    #pragma unroll
    for (int m = 32; m > 0; m >>= 1) s += __shfl_down(s, m);
    __shared__ float wsum[4];
    if ((threadIdx.x & 63) == 0) wsum[threadIdx.x >> 6] = s;
    __syncthreads();
    if (threadIdx.x == 0) {
        float ent = (wsum[0] + wsum[1]) + (wsum[2] + wsum[3]);
        out[(size_t)BB * DD * TT]     = 1.25f * (*sse) / (float)(BB * DD * TT);
        out[(size_t)BB * DD * TT + 1] = expf(-ent);
    }
}

extern "C" void kernel_launch(void* const* d_in, const int* in_sizes, int n_in,
                              void* d_out, int out_size, void* d_ws, size_t ws_size,
                              hipStream_t stream) {
    const float* z = (const float*)d_in[0];   // (32, 256, 1024) fp32
    const float* W = (const float*)d_in[1];   // (1024, 256) fp32
    float* out = (float*)d_out;               // 8388608 + 2 fp32

    float* wsq    = (float*)d_ws;
    float* rowsq  = wsq + 1024;
    int*   idxb   = (int*)(rowsq + NN);
    int*   counts = idxb + NN;
    float* sse    = (float*)(counts + 1024);

    prep_kernel<<<1024, 64, 0, stream>>>(W, wsq, counts, sse);
    rowsq_kernel<<<NN / 64, 256, 0, stream>>>(z, rowsq);
    argmin_kernel<<<NN / BROWS, 256, 0, stream>>>(z, W, wsq, rowsq, idxb, counts);
    gather_loss_kernel<<<BB * DD, 256, 0, stream>>>(z, W, idxb, out, sse);
    finalize_kernel<<<1, 256, 0, stream>>>(counts, sse, out);
}

// Round 2
// 358.365 us; speedup vs baseline: 1.6806x; 1.6806x over previous
//
#include <hip/hip_runtime.h>
#include <math.h>

// Problem dims (fixed by reference)
#define BB 32
#define DD 256
#define TT 1024
#define KK 1024
#define NN (BB*TT)          // 32768 rows

// argmin-GEMM tiling
#define BROWS 64            // rows per block
#define CCH   256           // codes per chunk
#define DSL   64            // d per slice

// ---------------------------------------------------------------------------
// ws layout (elements):
//   float wsq   [1024]      @ 0
//   float rowsq [32768]     @ 1024
//   int   idx   [32768]     @ 33792
//   int   counts[1024]      @ 66560
//   float sse   [1]         @ 67584
// ---------------------------------------------------------------------------

// wsq[k] = sum_d W[k,d]^2 (fp64 accumulate, round once -> closest to np pairwise)
// also zeroes counts and sse each launch (ws is poisoned / left dirty between calls)
__global__ void prep_kernel(const float* __restrict__ W, float* __restrict__ wsq,
                            int* __restrict__ counts, float* __restrict__ sse) {
    const int k = blockIdx.x;          // 1024 blocks, 64 threads (one wave)
    const int lane = threadIdx.x;
    const float4 v = ((const float4*)(W + (size_t)k * DD))[lane];
    double s = (double)v.x * v.x + (double)v.y * v.y + (double)v.z * v.z + (double)v.w * v.w;
    #pragma unroll
    for (int m = 32; m > 0; m >>= 1) s += __shfl_down(s, m);
    if (lane == 0) wsq[k] = (float)s;
    if (blockIdx.x < 16) counts[blockIdx.x * 64 + lane] = 0;
    if (blockIdx.x == 0 && lane == 0) *sse = 0.0f;
}

// rowsq[n] = sum_d z[b,d,t]^2 (fp64 accumulate, round once)
__global__ void rowsq_kernel(const float* __restrict__ z, float* __restrict__ rowsq) {
    __shared__ double p[4][64];
    const int lane = threadIdx.x & 63;
    const int grp  = threadIdx.x >> 6;
    const int row0 = blockIdx.x * 64;            // 512 blocks
    const int b = row0 >> 10;
    const int t = (row0 & 1023) + lane;
    const float* zp = z + (size_t)b * DD * TT + (size_t)grp * 64 * TT + t;
    double s = 0.0;
    #pragma unroll 4
    for (int d = 0; d < 64; ++d) { float v = zp[(size_t)d * TT]; s += (double)v * v; }
    p[grp][lane] = s;
    __syncthreads();
    if (threadIdx.x < 64) {
        double tot = (p[0][threadIdx.x] + p[1][threadIdx.x]) + (p[2][threadIdx.x] + p[3][threadIdx.x]);
        rowsq[row0 + threadIdx.x] = (float)tot;
    }
}

// swizzled float4 LDS index: bijective per row, spreads bank groups
__device__ __forceinline__ int swz(int r, int q) { return r * 16 + (q ^ ((r >> 3) & 7)); }

// One block: 64 rows x all 1024 codes, in 4 chunks of 256 codes.
// 256 threads = 8(ty) x 32(tx); per-thread 8 rows x 8 codes.
// dist mirrors np:  s1 = fl(rowsq + wsq);  v = fl(s1 - 2*dot)  (fmaf, exact 2*dot)
// Per-(row,code) dot is a single sequential fmaf chain over d=0..255 in order
// (bitwise-matches BLAS sgemm k-order; validated absmax==0.0). DO NOT reorder.
__global__ __launch_bounds__(256) void argmin_kernel(
    const float* __restrict__ z, const float* __restrict__ W,
    const float* __restrict__ wsq, const float* __restrict__ rowsq,
    int* __restrict__ idx_out, int* __restrict__ counts)
{
    __shared__ float4 zs[BROWS * 16];   // 16 KB
    __shared__ float4 ws[CCH * 16];     // 64 KB
    const int tid = threadIdx.x;
    const int tx = tid & 31, ty = tid >> 5;
    const int row0 = blockIdx.x * BROWS;
    const int b = row0 >> 10, t0 = row0 & 1023;
    const float* zbase = z + (size_t)b * DD * TT + t0;

    float minv[8]; int mini[8]; float rsq[8];
    #pragma unroll
    for (int i = 0; i < 8; ++i) {
        minv[i] = 3.4e38f; mini[i] = 0;
        rsq[i] = rowsq[row0 + ty * 8 + i];
    }

    const int zr = tid & 63;            // staging row (lane-coalesced over t)
    const int zqb = (tid >> 6) * 4;     // staging q-group base

    for (int ch = 0; ch < KK / CCH; ++ch) {
        float acc[8][8];
        #pragma unroll
        for (int i = 0; i < 8; ++i)
            #pragma unroll
            for (int j = 0; j < 8; ++j) acc[i][j] = 0.0f;

        for (int sl = 0; sl < DD / DSL; ++sl) {
            __syncthreads();   // protect LDS from previous compute phase
            // stage z slab: 64 rows x 64 d; gather 4 d's in regs -> one float4 write
            #pragma unroll
            for (int k = 0; k < 4; ++k) {
                int q = zqb + k;
                const float* zp = zbase + (size_t)(sl * DSL + q * 4) * TT + zr;
                float4 v;
                v.x = zp[0];
                v.y = zp[(size_t)TT];
                v.z = zp[(size_t)2 * TT];
                v.w = zp[(size_t)3 * TT];
                zs[swz(zr, q)] = v;
            }
            // stage W chunk: 256 codes x 64 d (global: contiguous float4)
            #pragma unroll
            for (int k = 0; k < 16; ++k) {
                int i4 = tid + k * 256;
                int r = i4 >> 4, q = i4 & 15;
                ws[swz(r, q)] = *(const float4*)(W + (size_t)(ch * CCH + r) * DD + sl * DSL + q * 4);
            }
            __syncthreads();
            // 8x8x(64d) register-tile FMA; d-order: q ascending, then x,y,z,w
            for (int q = 0; q < 16; ++q) {
                float4 zf[8], wf[8];
                #pragma unroll
                for (int i = 0; i < 8; ++i) zf[i] = zs[swz(ty * 8 + i, q)];
                #pragma unroll
                for (int j = 0; j < 8; ++j) wf[j] = ws[swz(tx * 8 + j, q)];
                #pragma unroll
                for (int i = 0; i < 8; ++i)
                    #pragma unroll
                    for (int j = 0; j < 8; ++j) {
                        acc[i][j] = fmaf(zf[i].x, wf[j].x, acc[i][j]);
                        acc[i][j] = fmaf(zf[i].y, wf[j].y, acc[i][j]);
                        acc[i][j] = fmaf(zf[i].z, wf[j].z, acc[i][j]);
                        acc[i][j] = fmaf(zf[i].w, wf[j].w, acc[i][j]);
                    }
            }
        }
        // score + running argmin (codes ascending -> first-min like np.argmin)
        #pragma unroll
        for (int j = 0; j < 8; ++j) {
            int c = ch * CCH + tx * 8 + j;
            float wq = wsq[c];
            #pragma unroll
            for (int i = 0; i < 8; ++i) {
                float s1 = rsq[i] + wq;                  // rounding 1 (matches np A+B)
                float v = fmaf(-2.0f, acc[i][j], s1);    // rounding 2 (matches np (A+B)-2P)
                if (v < minv[i]) { minv[i] = v; mini[i] = c; }
            }
        }
    }
    // reduce across the 32 tx lanes of each row; ties -> lowest index
    #pragma unroll
    for (int i = 0; i < 8; ++i) {
        float v = minv[i]; int ix = mini[i];
        #pragma unroll
        for (int m = 1; m < 32; m <<= 1) {
            float ov = __shfl_xor(v, m);
            int   oi = __shfl_xor(ix, m);
            if (ov < v || (ov == v && oi < ix)) { v = ov; ix = oi; }
        }
        if (tx == 0) {
            int row = row0 + ty * 8 + i;
            idx_out[row] = ix;
            atomicAdd(&counts[ix], 1);
        }
    }
}

// out[b,d,t] = fl(ze + fl(W[idx]-ze))  (straight-through, matches np roundings)
// sse += sum (W[idx]-ze)^2
__global__ void gather_loss_kernel(const float* __restrict__ z, const float* __restrict__ W,
                                   const int* __restrict__ idx, float* __restrict__ out,
                                   float* __restrict__ sse) {
    const int bd = blockIdx.x;              // 8192 blocks = B*D
    const int b = bd >> 8, d = bd & 255;
    const int t = threadIdx.x * 4;
    const int4 ix = *(const int4*)(idx + b * TT + t);
    const size_t base = (size_t)b * DD * TT + (size_t)d * TT + t;
    const float4 zv = *(const float4*)(z + base);
    float4 w;
    w.x = W[(size_t)ix.x * DD + d];
    w.y = W[(size_t)ix.y * DD + d];
    w.z = W[(size_t)ix.z * DD + d];
    w.w = W[(size_t)ix.w * DD + d];
    float ex = w.x - zv.x, ey = w.y - zv.y, ez = w.z - zv.z, ew = w.w - zv.w;
    float4 o;
    o.x = zv.x + ex; o.y = zv.y + ey; o.z = zv.z + ez; o.w = zv.w + ew;
    *(float4*)(out + base) = o;
    float local = (ex * ex + ey * ey) + (ez * ez + ew * ew);
    #pragma unroll
    for (int m = 32; m > 0; m >>= 1) local += __shfl_down(local, m);
    __shared__ float wsum[4];
    if ((threadIdx.x & 63) == 0) wsum[threadIdx.x >> 6] = local;
    __syncthreads();
    if (threadIdx.x == 0) atomicAdd(sse, (wsum[0] + wsum[1]) + (wsum[2] + wsum[3]));
}

// reg_loss = 1.25 * sse / numel ; perplexity = exp(-sum p*log(p+1e-10))
__global__ void finalize_kernel(const int* __restrict__ counts, const float* __restrict__ sse,
                                float* __restrict__ out) {
    float s = 0.0f;
    for (int k = threadIdx.x; k < KK; k += 256) {
        float p = (float)counts[k] / (float)NN;
        s += p * logf(p + 1e-10f);
    }
    #pragma unroll
    for (int m = 32; m > 0; m >>= 1) s += __shfl_down(s, m);
    __shared__ float wsum[4];
    if ((threadIdx.x & 63) == 0) wsum[threadIdx.x >> 6] = s;
    __syncthreads();
    if (threadIdx.x == 0) {
        float ent = (wsum[0] + wsum[1]) + (wsum[2] + wsum[3]);
        out[(size_t)BB * DD * TT]     = 1.25f * (*sse) / (float)(BB * DD * TT);
        out[(size_t)BB * DD * TT + 1] = expf(-ent);
    }
}

extern "C" void kernel_launch(void* const* d_in, const int* in_sizes, int n_in,
                              void* d_out, int out_size, void* d_ws, size_t ws_size,
                              hipStream_t stream) {
    const float* z = (const float*)d_in[0];   // (32, 256, 1024) fp32
    const float* W = (const float*)d_in[1];   // (1024, 256) fp32
    float* out = (float*)d_out;               // 8388608 + 2 fp32

    float* wsq    = (float*)d_ws;
    float* rowsq  = wsq + 1024;
    int*   idxb   = (int*)(rowsq + NN);
    int*   counts = idxb + NN;
    float* sse    = (float*)(counts + 1024);

    prep_kernel<<<1024, 64, 0, stream>>>(W, wsq, counts, sse);
    rowsq_kernel<<<NN / 64, 256, 0, stream>>>(z, rowsq);
    argmin_kernel<<<NN / BROWS, 256, 0, stream>>>(z, W, wsq, rowsq, idxb, counts);
    gather_loss_kernel<<<BB * DD, 256, 0, stream>>>(z, W, idxb, out, sse);
    finalize_kernel<<<1, 256, 0, stream>>>(counts, sse, out);
}

// Round 3
// 272.222 us; speedup vs baseline: 2.2125x; 1.3164x over previous
//
#include <hip/hip_runtime.h>
#include <math.h>

// Problem dims (fixed by reference)
#define BB 32
#define DD 256
#define TT 1024
#define KK 1024
#define NN (BB*TT)          // 32768 rows

// argmin-GEMM tiling
#define BROWS 64            // rows per block
#define CCH   256           // codes per chunk
#define DSL   64            // d per slice
#define NSTEP 16            // 4 chunks x 4 slices

// ---------------------------------------------------------------------------
// ws layout (elements): float wsq[1024] @0 ; int counts[1024] @1024 ; float sse @2048
// ---------------------------------------------------------------------------

// wsq[k] = sum_d W[k,d]^2 (fp64 accumulate, round once). Zeroes counts+sse.
__global__ void prep_kernel(const float* __restrict__ W, float* __restrict__ wsq,
                            int* __restrict__ counts, float* __restrict__ sse) {
    const int k = blockIdx.x;          // 1024 blocks, 64 threads
    const int lane = threadIdx.x;
    const float4 v = ((const float4*)(W + (size_t)k * DD))[lane];
    double s = (double)v.x * v.x + (double)v.y * v.y + (double)v.z * v.z + (double)v.w * v.w;
    #pragma unroll
    for (int m = 32; m > 0; m >>= 1) s += __shfl_down(s, m);
    if (lane == 0) wsq[k] = (float)s;
    if (blockIdx.x < 16) counts[blockIdx.x * 64 + lane] = 0;
    if (blockIdx.x == 0 && lane == 0) *sse = 0.0f;
}

// W LDS slots: value at (r, slot) is W[..r..][4*(slot ^ sw(r))..]; read at slot = q ^ sw(r).
__device__ __forceinline__ int swz_w(int r, int q) { return r * 16 + (q ^ ((r >> 3) & 7)); }
// z slots: extra ^(r&7) term -> staging writes (lanes sweep r) are 2-way/phase (free);
// reads are ty-broadcast so their bank pattern is irrelevant.
__device__ __forceinline__ int swz_z(int r, int q) { return r * 16 + (q ^ (r & 7) ^ ((r >> 3) & 7)); }

// async global->LDS, 16B per lane; LDS dest = wave-uniform base + lane*16 (linear).
__device__ __forceinline__ void gl_lds16(const float* g, void* l) {
    __builtin_amdgcn_global_load_lds((const __attribute__((address_space(1))) void*)g,
                                     (__attribute__((address_space(3))) void*)l, 16, 0, 0);
}

// Fused: rowsq + argmin-GEMM + gather/straight-through/SSE/counts.
// Block: 64 rows x all 1024 codes (4 chunks of 256). 256 thr = 8(ty) x 32(tx), 8x8 tile.
// dist mirrors np:  s1 = fl(rowsq + wsq);  v = fmaf(-2, dot, s1).
// Per-(row,code) dot: single sequential fmaf chain over d=0..255 in order
// (bitwise-matches BLAS k-order; validated absmax==0.0 twice). DO NOT reorder.
__global__ __launch_bounds__(256, 2) void vq_fused_kernel(
    const float* __restrict__ z, const float* __restrict__ W,
    const float* __restrict__ wsq, float* __restrict__ out,
    int* __restrict__ counts, float* __restrict__ sse)
{
    __shared__ float4 zs[BROWS * 16];   // 16 KB (reused as idx/sse scratch at the end)
    __shared__ float4 ws[CCH * 16];     // 64 KB
    const int tid = threadIdx.x;
    const int tx = tid & 31, ty = tid >> 5;
    const int w = tid >> 6, lane = tid & 63;
    const int row0 = blockIdx.x * BROWS;
    const int b = row0 >> 10, t0 = row0 & 1023;
    const size_t bbase = (size_t)b * DD * TT;
    const float* zbase = z + bbase + t0;

    // ---- phase 0: per-wave rowsq (fp64, bitwise == ((g0+g1)+(g2+g3)) of 64-elem chains)
    float rsq[8];
    {
        const int ro = lane & 15;          // row offset within wave's 16 rows
        const int g  = lane >> 4;          // d-quarter 0..3
        const float* zp = zbase + (size_t)g * 64 * TT + (16 * w + ro);
        double s = 0.0;
        #pragma unroll 4
        for (int d = 0; d < 64; ++d) { float v = zp[(size_t)d * TT]; s += (double)v * v; }
        s += __shfl_xor(s, 16);            // g0+g1 / g2+g3 (fp64 add commutative: bitwise safe)
        s += __shfl_xor(s, 32);            // (g0+g1)+(g2+g3)
        float f = (float)s;
        #pragma unroll
        for (int i = 0; i < 8; ++i) rsq[i] = __shfl(f, (ty & 1) * 8 + i);
    }

    float minv[8]; int mini[8];
    #pragma unroll
    for (int i = 0; i < 8; ++i) { minv[i] = 3.4e38f; mini[i] = 0; }

    // z-prefetch registers (next step's slab); staging identity: thread covers
    // row zr = lane (wait: rows 0..63 = tid&63), q-group 4w..4w+3
    const int zr = tid & 63;
    const int zq0 = w * 4;
    float4 zreg[4];
    {   // prologue: load slab for step 0 (sl=0)
        #pragma unroll
        for (int j = 0; j < 4; ++j) {
            const float* zp = zbase + (size_t)((zq0 + j) * 4) * TT + zr;
            zreg[j].x = zp[0]; zreg[j].y = zp[(size_t)TT];
            zreg[j].z = zp[(size_t)2 * TT]; zreg[j].w = zp[(size_t)3 * TT];
        }
    }

    const int wr0 = w * 64 + (lane >> 4); // W-stage row for k=0
    const int wslot = lane & 15;
    char* const wlbase = (char*)ws + (size_t)w * 16384;

    float acc[8][8];
    float wq[8];

    for (int s = 0; s < NSTEP; ++s) {
        const int sl = s & 3, ch = s >> 2;
        __syncthreads();   // waves done reading zs/ws of previous step; z-prefetch drained
        // write z slab from regs (4x ds_write_b128, 2-way/phase swizzle)
        #pragma unroll
        for (int j = 0; j < 4; ++j) zs[swz_z(zr, zq0 + j)] = zreg[j];
        // stage W chunk-slice direct to LDS: linear dest, pre-swizzled source
        {
            const float* wch = W + (size_t)(ch * CCH) * DD + sl * DSL;
            #pragma unroll
            for (int k = 0; k < 16; ++k) {
                int r = wr0 + k * 4;
                const float* g = wch + (size_t)r * DD + 4 * (wslot ^ ((r >> 3) & 7));
                gl_lds16(g, wlbase + k * 1024);
            }
        }
        __syncthreads();   // drains lgkm (zs) + vmcnt (W loads) [compiler-inserted]

        if (sl == 0) {
            #pragma unroll
            for (int i = 0; i < 8; ++i)
                #pragma unroll
                for (int j = 0; j < 8; ++j) acc[i][j] = 0.0f;
            #pragma unroll
            for (int j = 0; j < 8; ++j) wq[j] = wsq[ch * CCH + tx * 8 + j];
        }
        // prefetch next step's z slab into regs (hides under compute)
        if (s < NSTEP - 1) {
            const int sln = (s + 1) & 3;
            #pragma unroll
            for (int j = 0; j < 4; ++j) {
                const float* zp = zbase + (size_t)(sln * DSL + (zq0 + j) * 4) * TT + zr;
                zreg[j].x = zp[0]; zreg[j].y = zp[(size_t)TT];
                zreg[j].z = zp[(size_t)2 * TT]; zreg[j].w = zp[(size_t)3 * TT];
            }
        }
        // 8x8x(64d) register-tile FMA; d-order: q ascending, then x,y,z,w
        for (int q = 0; q < 16; ++q) {
            float4 zf[8], wf[8];
            #pragma unroll
            for (int i = 0; i < 8; ++i) zf[i] = zs[swz_z(ty * 8 + i, q)];
            #pragma unroll
            for (int j = 0; j < 8; ++j) wf[j] = ws[swz_w(tx * 8 + j, q)];
            #pragma unroll
            for (int i = 0; i < 8; ++i)
                #pragma unroll
                for (int j = 0; j < 8; ++j) {
                    acc[i][j] = fmaf(zf[i].x, wf[j].x, acc[i][j]);
                    acc[i][j] = fmaf(zf[i].y, wf[j].y, acc[i][j]);
                    acc[i][j] = fmaf(zf[i].z, wf[j].z, acc[i][j]);
                    acc[i][j] = fmaf(zf[i].w, wf[j].w, acc[i][j]);
                }
        }
        if (sl == 3) {
            // score + running argmin (codes ascending -> first-min like np.argmin)
            #pragma unroll
            for (int j = 0; j < 8; ++j) {
                int c = ch * CCH + tx * 8 + j;
                #pragma unroll
                for (int i = 0; i < 8; ++i) {
                    float s1 = rsq[i] + wq[j];               // rounding 1 (np A+B)
                    float v = fmaf(-2.0f, acc[i][j], s1);    // rounding 2 (np (A+B)-2P)
                    if (v < minv[i]) { minv[i] = v; mini[i] = c; }
                }
            }
        }
    }

    __syncthreads();           // all compute done; zs becomes scratch
    int* idxs = (int*)zs;      // 64 ints
    float* ssescr = (float*)zs + 64;
    // reduce across the 32 tx lanes of each row; ties -> lowest index
    #pragma unroll
    for (int i = 0; i < 8; ++i) {
        float v = minv[i]; int ix = mini[i];
        #pragma unroll
        for (int m = 1; m < 32; m <<= 1) {
            float ov = __shfl_xor(v, m);
            int   oi = __shfl_xor(ix, m);
            if (ov < v || (ov == v && oi < ix)) { v = ov; ix = oi; }
        }
        if (tx == 0) {
            idxs[ty * 8 + i] = ix;
            atomicAdd(&counts[ix], 1);
        }
    }
    __syncthreads();

    // ---- fused gather / straight-through / SSE over this block's 64 rows x 256 d
    const int tg = tid & 15;       // t-quarter (4 rows)
    const int dg = tid >> 4;       // 16 d-groups of 16
    const int t4 = tg * 4;
    int ixs[4];
    #pragma unroll
    for (int m = 0; m < 4; ++m) ixs[m] = idxs[t4 + m];
    float ssel = 0.0f;
    #pragma unroll
    for (int k4 = 0; k4 < 4; ++k4) {
        const int d0 = dg * 16 + k4 * 4;
        float wr[4][4];
        #pragma unroll
        for (int m = 0; m < 4; ++m) {
            float4 wv = *(const float4*)(W + (size_t)ixs[m] * DD + d0);
            wr[m][0] = wv.x; wr[m][1] = wv.y; wr[m][2] = wv.z; wr[m][3] = wv.w;
        }
        #pragma unroll
        for (int dd = 0; dd < 4; ++dd) {
            const int d = d0 + dd;
            const size_t base = bbase + (size_t)d * TT + t0 + t4;
            float4 zv = *(const float4*)(z + base);
            float e0 = wr[0][dd] - zv.x, e1 = wr[1][dd] - zv.y;
            float e2 = wr[2][dd] - zv.z, e3 = wr[3][dd] - zv.w;
            float4 o;
            o.x = zv.x + e0; o.y = zv.y + e1; o.z = zv.z + e2; o.w = zv.w + e3;
            *(float4*)(out + base) = o;
            ssel += (e0 * e0 + e1 * e1) + (e2 * e2 + e3 * e3);
        }
    }
    #pragma unroll
    for (int m = 32; m > 0; m >>= 1) ssel += __shfl_down(ssel, m);
    if (lane == 0) ssescr[w] = ssel;
    __syncthreads();
    if (tid == 0) atomicAdd(sse, (ssescr[0] + ssescr[1]) + (ssescr[2] + ssescr[3]));
}

// reg_loss = 1.25 * sse / numel ; perplexity = exp(-sum p*log(p+1e-10))
__global__ void finalize_kernel(const int* __restrict__ counts, const float* __restrict__ sse,
                                float* __restrict__ out) {
    float s = 0.0f;
    for (int k = threadIdx.x; k < KK; k += 256) {
        float p = (float)counts[k] / (float)NN;
        s += p * logf(p + 1e-10f);
    }
    #pragma unroll
    for (int m = 32; m > 0; m >>= 1) s += __shfl_down(s, m);
    __shared__ float wsum[4];
    if ((threadIdx.x & 63) == 0) wsum[threadIdx.x >> 6] = s;
    __syncthreads();
    if (threadIdx.x == 0) {
        float ent = (wsum[0] + wsum[1]) + (wsum[2] + wsum[3]);
        out[(size_t)BB * DD * TT]     = 1.25f * (*sse) / (float)(BB * DD * TT);
        out[(size_t)BB * DD * TT + 1] = expf(-ent);
    }
}

extern "C" void kernel_launch(void* const* d_in, const int* in_sizes, int n_in,
                              void* d_out, int out_size, void* d_ws, size_t ws_size,
                              hipStream_t stream) {
    const float* z = (const float*)d_in[0];   // (32, 256, 1024) fp32
    const float* W = (const float*)d_in[1];   // (1024, 256) fp32
    float* out = (float*)d_out;               // 8388608 + 2 fp32

    float* wsq    = (float*)d_ws;
    int*   counts = (int*)(wsq + 1024);
    float* sse    = (float*)(counts + 1024);

    prep_kernel<<<1024, 64, 0, stream>>>(W, wsq, counts, sse);
    vq_fused_kernel<<<NN / BROWS, 256, 0, stream>>>(z, W, wsq, out, counts, sse);
    finalize_kernel<<<1, 256, 0, stream>>>(counts, sse, out);
}